// Round 3
// baseline (602.830 us; speedup 1.0000x reference)
//
#include <hip/hip_runtime.h>
#include <hip/hip_bf16.h>

typedef __bf16 bf16x8 __attribute__((ext_vector_type(8)));
typedef float  f32x4  __attribute__((ext_vector_type(4)));

// ---------------- build x_in(bf16) = [kg_emb[node_id] | ccle_mlp(ccle)[node_id]] ----------------
__global__ __launch_bounds__(256) void build_x_kernel(
    const float* __restrict__ kg_emb, const float* __restrict__ ccle,
    const float* __restrict__ cw1, const float* __restrict__ cb1,
    const float* __restrict__ cw2, const float* __restrict__ cb2,
    const int* __restrict__ node_id, __bf16* __restrict__ x_in, int Nn)
{
    __shared__ float h[2][32];
    int sub = threadIdx.x >> 7;       // 2 nodes per block
    int t   = threadIdx.x & 127;
    int i   = blockIdx.x * 2 + sub;
    if (i < Nn && t < 32) {
        int kid = node_id[i];
        float a = 0.f;
        #pragma unroll
        for (int j = 0; j < 4; j++) a += ccle[kid*4 + j] * cw1[j*32 + t];
        a += cb1[t];
        h[sub][t] = a < 0.f ? 0.01f * a : a;
    }
    __syncthreads();
    if (i < Nn) {
        int kid = node_id[i];
        x_in[i*256 + t] = (__bf16)kg_emb[kid*128 + t];
        float a = 0.f;
        #pragma unroll
        for (int j = 0; j < 32; j++) a += h[sub][j] * cw2[j*128 + t];
        a += cb2[t];
        x_in[i*256 + 128 + t] = (__bf16)a;
    }
}

// ---------------- CSR build ----------------
__global__ void hist_kernel(const int* __restrict__ ei, int* __restrict__ deg, int E) {
    int e = blockIdx.x * 256 + threadIdx.x;
    if (e < E) atomicAdd(&deg[ei[E + e]], 1);
}

__global__ __launch_bounds__(1024) void scan_kernel(
    const int* __restrict__ deg, int* __restrict__ row_off, int* __restrict__ cursor, int Nn)
{
    __shared__ int wsum[16];
    __shared__ int carry_s;
    int t = threadIdx.x;
    int lane = t & 63, wid = t >> 6;
    if (t == 0) carry_s = 0;
    __syncthreads();
    for (int base = 0; base < Nn; base += 1024) {
        int idx = base + t;
        int v = (idx < Nn) ? deg[idx] : 0;
        int incl = v;
        #pragma unroll
        for (int off = 1; off < 64; off <<= 1) {
            int x = __shfl_up(incl, off, 64);
            if (lane >= off) incl += x;
        }
        if (lane == 63) wsum[wid] = incl;
        __syncthreads();
        if (wid == 0) {
            int wv = (lane < 16) ? wsum[lane] : 0;
            #pragma unroll
            for (int off = 1; off < 16; off <<= 1) {
                int x = __shfl_up(wv, off, 64);
                if (lane >= off) wv += x;
            }
            if (lane < 16) wsum[lane] = wv;
        }
        __syncthreads();
        int wprefix = (wid > 0) ? wsum[wid - 1] : 0;
        int excl = carry_s + wprefix + incl - v;
        if (idx < Nn) { row_off[idx] = excl; cursor[idx] = excl; }
        __syncthreads();
        if (t == 1023) carry_s += wsum[15];
        __syncthreads();
    }
    if (t == 0) row_off[Nn] = carry_s;
}

__global__ void scatter_kernel(const int* __restrict__ ei, const int* __restrict__ et,
                               int* __restrict__ cursor, int* __restrict__ cidx, int E) {
    int e = blockIdx.x * 256 + threadIdx.x;
    if (e < E) {
        int d = ei[E + e];
        int pos = atomicAdd(&cursor[d], 1);
        cidx[pos] = (et[e] << 20) | ei[e];   // src < 2^20, et < 8
    }
}

// ---------------- 64x64-tile transpose + fp32->bf16 convert ----------------
__global__ __launch_bounds__(256) void transpose_kernel(
    const float* __restrict__ B, __bf16* __restrict__ Bt)
{
    __shared__ __bf16 tile[64][65];
    int z = blockIdx.z;
    int kb = blockIdx.x * 64;
    int nb = blockIdx.y * 64;
    int t = threadIdx.x;
    const float* Bz = B + z * 65536;
    __bf16* Btz = Bt + z * 65536;
    for (int idx = t; idx < 4096; idx += 256) {
        int rr = idx >> 6, cc = idx & 63;
        tile[rr][cc] = (__bf16)Bz[(kb + rr) * 256 + nb + cc];
    }
    __syncthreads();
    for (int idx = t; idx < 4096; idx += 256) {
        int rr = idx >> 6, cc = idx & 63;
        Btz[(nb + rr) * 256 + kb + cc] = tile[cc][rr];
    }
}

// ---------------- direct-from-global MFMA GEMM (no LDS, no barriers) ----------------
// C[z][M][256] = A[M][256] @ Bt[z][256][256]^T, tiles 128x128.
// 1D grid with XCD swizzle: id%8 = XCD; blocks sharing one A-tile (2 n-blocks x R
// relations = R2 members) get consecutive slots on one XCD -> A re-reads hit its L2.
__global__ __launch_bounds__(256, 2) void gemm_direct_kernel(
    const __bf16* __restrict__ A,
    const __bf16* __restrict__ Bt, long bStride,
    __bf16* __restrict__ C, long cStride,
    const float* __restrict__ bias, float slope,
    int M, int R2, int mb)
{
    const int id = blockIdx.x;
    const int xcd = id & 7, slot = id >> 3;
    const int g = xcd + 8 * (slot / R2);      // m-tile index
    const int member = slot % R2;
    if (g >= mb) return;
    const int m0 = g * 128, n0 = (member & 1) * 128;
    const int z = member >> 1;
    const __bf16* __restrict__ Bb = Bt + (long)z * bStride;
    __bf16* __restrict__ Cb = C + (long)z * cStride;

    const int t = threadIdx.x;
    const int wave = t >> 6, lane = t & 63;
    const int wy = (wave >> 1) * 64, wx = (wave & 1) * 64;
    const int lr = lane & 15, lq = lane >> 4;

    // per-lane fragment row offsets (elements); A rows clamped for tail tile
    int aoff[4], boff[4];
    #pragma unroll
    for (int tm = 0; tm < 4; tm++) {
        int r = m0 + wy + tm * 16 + lr;
        if (r >= M) r = M - 1;
        aoff[tm] = r * 256 + lq * 8;
    }
    #pragma unroll
    for (int tn = 0; tn < 4; tn++)
        boff[tn] = (n0 + wx + tn * 16 + lr) * 256 + lq * 8;

    f32x4 acc[4][4];
    #pragma unroll
    for (int a_ = 0; a_ < 4; a_++)
        #pragma unroll
        for (int b_ = 0; b_ < 4; b_++) acc[a_][b_] = (f32x4){0.f, 0.f, 0.f, 0.f};

    #pragma unroll
    for (int k0 = 0; k0 < 256; k0 += 32) {
        bf16x8 af[4], bfr[4];
        #pragma unroll
        for (int tm = 0; tm < 4; tm++) af[tm]  = *(const bf16x8*)(A  + aoff[tm] + k0);
        #pragma unroll
        for (int tn = 0; tn < 4; tn++) bfr[tn] = *(const bf16x8*)(Bb + boff[tn] + k0);
        #pragma unroll
        for (int tm = 0; tm < 4; tm++)
            #pragma unroll
            for (int tn = 0; tn < 4; tn++)
                acc[tm][tn] = __builtin_amdgcn_mfma_f32_16x16x32_bf16(af[tm], bfr[tn], acc[tm][tn], 0, 0, 0);
    }

    #pragma unroll
    for (int tm = 0; tm < 4; tm++) {
        #pragma unroll
        for (int tn = 0; tn < 4; tn++) {
            int col = n0 + wx + tn * 16 + lr;
            float bcol = bias ? bias[col] : 0.f;
            #pragma unroll
            for (int ii = 0; ii < 4; ii++) {
                int rg = m0 + wy + tm * 16 + lq * 4 + ii;
                if (rg < M) {
                    float v = acc[tm][tn][ii] + bcol;
                    v = v < 0.f ? v * slope : v;
                    Cb[(long)rg * 256 + col] = (__bf16)v;
                }
            }
        }
    }
}

// ---------------- s_q[r,n,h] = xw[r,n,:]@q[:,h], s_k likewise ----------------
__global__ __launch_bounds__(256) void sqk_kernel(
    const __bf16* __restrict__ XW, const float* __restrict__ q,
    const float* __restrict__ k, float* __restrict__ s_q,
    float* __restrict__ s_k, int Nn)
{
    __shared__ float qk[8][260];
    int t = threadIdx.x;
    for (int idx = t; idx < 2048; idx += 256) {
        int h8 = idx & 7, kk = idx >> 3;
        qk[h8][kk] = (h8 < 4) ? q[kk * 4 + h8] : k[kk * 4 + (h8 - 4)];
    }
    __syncthreads();
    int r = blockIdx.y;
    int node = blockIdx.x * 32 + (t >> 3);
    int h8 = t & 7;
    if (node >= Nn) return;
    const __bf16* row = XW + ((long)r * Nn + node) * 256;
    float acc = 0.f;
    for (int kb = 0; kb < 256; kb += 8) {
        uint4 pv = *(const uint4*)(row + kb);
        const __bf16* pp = (const __bf16*)&pv;
        #pragma unroll
        for (int j = 0; j < 8; j++) acc += (float)pp[j] * qk[h8][kb + j];
    }
    if (h8 < 4) s_q[((long)r * Nn + node) * 4 + h8] = acc;
    else        s_k[((long)r * Nn + node) * 4 + (h8 - 4)] = acc;
}

// ---------------- attention softmax + aggregation, one wave per node ----------------
// Single pass (no segment-max: logits are O(10) here; exp arg clamped at 40).
// Half-wave edge pairs: lanes 0-31 process edge j, lanes 32-63 edge j+1;
// each lane gathers 8 contiguous bf16 (16 B) of the source row.
__global__ __launch_bounds__(256) void agg_kernel(
    const __bf16* __restrict__ XW, const float* __restrict__ s_q,
    const float* __restrict__ s_k, const int* __restrict__ row_off,
    const int* __restrict__ cidx, const float* __restrict__ bias,
    const __bf16* __restrict__ skipb, __bf16* __restrict__ outb,
    float* __restrict__ outf, float slope, int Nn)
{
    int lane = threadIdx.x & 63;
    int i = blockIdx.x * 4 + (threadIdx.x >> 6);
    if (i >= Nn) return;
    int base = row_off[i];
    int deg = row_off[i + 1] - base;

    int half = lane >> 5;
    int l32 = lane & 31;
    int myh = l32 >> 3;          // head owning my 8 dims
    int d8 = l32 * 8;            // my dim offset within the 256-row

    float acc[8];
    #pragma unroll
    for (int u = 0; u < 8; u++) acc[u] = 0.f;
    float ss0 = 0.f, ss1 = 0.f, ss2 = 0.f, ss3 = 0.f;

    for (int c0 = 0; c0 < deg; c0 += 64) {
        int e = c0 + lane;
        float p0 = 0.f, p1 = 0.f, p2 = 0.f, p3 = 0.f;
        int cc = 0;
        if (e < deg) {
            cc = cidx[base + e];
            int src = cc & 0xFFFFF, et = cc >> 20;
            const float* sq = s_q + ((long)et * Nn + i) * 4;
            const float* sk = s_k + ((long)et * Nn + src) * 4;
            float l0 = sq[0] + sk[0]; l0 = l0 < 0.f ? 0.2f * l0 : l0;
            float l1 = sq[1] + sk[1]; l1 = l1 < 0.f ? 0.2f * l1 : l1;
            float l2 = sq[2] + sk[2]; l2 = l2 < 0.f ? 0.2f * l2 : l2;
            float l3 = sq[3] + sk[3]; l3 = l3 < 0.f ? 0.2f * l3 : l3;
            p0 = __expf(fminf(l0, 40.f)); p1 = __expf(fminf(l1, 40.f));
            p2 = __expf(fminf(l2, 40.f)); p3 = __expf(fminf(l3, 40.f));
        }
        ss0 += p0; ss1 += p1; ss2 += p2; ss3 += p3;
        int cnt = min(64, deg - c0);
        for (int j = 0; j < cnt; j += 2) {
            int srcl = j + half;             // lane holding my edge's p/cc (p=0 past tail)
            float q0 = __shfl(p0, srcl, 64);
            float q1 = __shfl(p1, srcl, 64);
            float q2 = __shfl(p2, srcl, 64);
            float q3 = __shfl(p3, srcl, 64);
            int   cj = __shfl(cc, srcl, 64);
            float w = (myh & 2) ? ((myh & 1) ? q3 : q2) : ((myh & 1) ? q1 : q0);
            int src = cj & 0xFFFFF, et = cj >> 20;
            bf16x8 xv = *(const bf16x8*)(XW + ((long)et * Nn + src) * 256 + d8);
            #pragma unroll
            for (int u = 0; u < 8; u++) acc[u] += w * (float)xv[u];
        }
    }
    // combine the two halves (each covered alternating edges of the same node)
    #pragma unroll
    for (int u = 0; u < 8; u++) acc[u] += __shfl_xor(acc[u], 32, 64);
    // reduce softmax denominators across the wave
    #pragma unroll
    for (int off = 32; off >= 1; off >>= 1) {
        ss0 += __shfl_xor(ss0, off, 64);
        ss1 += __shfl_xor(ss1, off, 64);
        ss2 += __shfl_xor(ss2, off, 64);
        ss3 += __shfl_xor(ss3, off, 64);
    }
    float ssh = (myh & 2) ? ((myh & 1) ? ss3 : ss2) : ((myh & 1) ? ss1 : ss0);
    float inv = 1.f / fmaxf(ssh, 1e-16f);

    float vout[8];
    #pragma unroll
    for (int u = 0; u < 8; u++) {
        float v = acc[u] * inv + bias[d8 + u];
        if (skipb) v += (float)skipb[(long)i * 256 + d8 + u];
        vout[u] = v < 0.f ? slope * v : v;
    }
    if (outb) {
        if (half == 0) {
            __bf16 tmp[8];
            #pragma unroll
            for (int u = 0; u < 8; u++) tmp[u] = (__bf16)vout[u];
            *(uint4*)(outb + (long)i * 256 + d8) = *(const uint4*)tmp;
        }
    } else {
        // fp32 out: half 0 stores first 4, half 1 stores last 4
        float4 f4;
        if (half == 0) { f4 = make_float4(vout[0], vout[1], vout[2], vout[3]);
                         *(float4*)(outf + (long)i * 256 + d8) = f4; }
        else           { f4 = make_float4(vout[4], vout[5], vout[6], vout[7]);
                         *(float4*)(outf + (long)i * 256 + d8 + 4) = f4; }
    }
}

extern "C" void kernel_launch(void* const* d_in, const int* in_sizes, int n_in,
                              void* d_out, int out_size, void* d_ws, size_t ws_size,
                              hipStream_t stream)
{
    const float* kg_emb  = (const float*)d_in[0];
    const float* ccle    = (const float*)d_in[1];
    const int*   node_id = (const int*)d_in[2];
    const int*   edge_ix = (const int*)d_in[3];
    const int*   edge_ty = (const int*)d_in[4];
    const float* ccle_w1 = (const float*)d_in[5];
    const float* ccle_b1 = (const float*)d_in[6];
    const float* ccle_w2 = (const float*)d_in[7];
    const float* ccle_b2 = (const float*)d_in[8];
    const float* w1      = (const float*)d_in[9];
    const float* q1      = (const float*)d_in[10];
    const float* k1      = (const float*)d_in[11];
    const float* bias1   = (const float*)d_in[12];
    const float* w2      = (const float*)d_in[13];
    const float* q2      = (const float*)d_in[14];
    const float* k2      = (const float*)d_in[15];
    const float* bias2   = (const float*)d_in[16];
    const float* skip_w1 = (const float*)d_in[17];
    const float* skip_b1 = (const float*)d_in[18];
    const float* skip_w2 = (const float*)d_in[19];
    const float* skip_b2 = (const float*)d_in[20];

    const int Nn = in_sizes[2];
    const int E  = in_sizes[4];
    const int R  = in_sizes[9] / (256 * 256);

    // workspace carve
    char* p = (char*)d_ws;
    auto alloc = [&](size_t bytes) { char* r = p; p += (bytes + 255) & ~(size_t)255; return r; };
    __bf16* x_in  = (__bf16*)alloc((size_t)Nn * 256 * 2);
    __bf16* x1    = (__bf16*)alloc((size_t)Nn * 256 * 2);
    __bf16* sh    = (__bf16*)alloc((size_t)Nn * 256 * 2);
    __bf16* skipb = (__bf16*)alloc((size_t)Nn * 256 * 2);
    __bf16* XW    = (__bf16*)alloc((size_t)R * Nn * 256 * 2);
    float*  s_q   = (float*)alloc((size_t)R * Nn * 4 * 4);
    float*  s_k   = (float*)alloc((size_t)R * Nn * 4 * 4);
    __bf16* w1t   = (__bf16*)alloc((size_t)R * 65536 * 2);
    __bf16* w2t   = (__bf16*)alloc((size_t)R * 65536 * 2);
    __bf16* sw1t  = (__bf16*)alloc((size_t)65536 * 2);
    __bf16* sw2t  = (__bf16*)alloc((size_t)65536 * 2);
    int* deg     = (int*)alloc((size_t)Nn * 4);
    int* row_off = (int*)alloc((size_t)(Nn + 1) * 4);
    int* cursor  = (int*)alloc((size_t)Nn * 4);
    int* cidx    = (int*)alloc((size_t)E * 4);

    const int mb = (Nn + 127) / 128;
    const int eb = (E + 255) / 256;
    const int grp = (mb + 7) / 8;
    const int R2 = 2 * R;
    const int gemmR_blocks = 8 * grp * R2;   // batched-R gemm
    const int gemm1_blocks = 8 * grp * 2;    // single-matrix gemm

    (void)hipMemsetAsync(deg, 0, (size_t)Nn * 4, stream);
    build_x_kernel<<<dim3((Nn + 1) / 2), 256, 0, stream>>>(
        kg_emb, ccle, ccle_w1, ccle_b1, ccle_w2, ccle_b2, node_id, x_in, Nn);
    hist_kernel<<<dim3(eb), 256, 0, stream>>>(edge_ix, deg, E);
    scan_kernel<<<dim3(1), 1024, 0, stream>>>(deg, row_off, cursor, Nn);
    scatter_kernel<<<dim3(eb), 256, 0, stream>>>(edge_ix, edge_ty, cursor, cidx, E);
    transpose_kernel<<<dim3(4, 4, R), 256, 0, stream>>>(w1, w1t);
    transpose_kernel<<<dim3(4, 4, R), 256, 0, stream>>>(w2, w2t);
    transpose_kernel<<<dim3(4, 4, 1), 256, 0, stream>>>(skip_w1, sw1t);
    transpose_kernel<<<dim3(4, 4, 1), 256, 0, stream>>>(skip_w2, sw2t);

    // layer 1: XW = x_in @ w1[r]
    gemm_direct_kernel<<<dim3(gemmR_blocks), 256, 0, stream>>>(
        x_in, w1t, 65536L, XW, (long)Nn * 256, nullptr, 1.0f, Nn, R2, mb);
    sqk_kernel<<<dim3((Nn + 31) / 32, R), 256, 0, stream>>>(XW, q1, k1, s_q, s_k, Nn);
    agg_kernel<<<dim3((Nn + 3) / 4), 256, 0, stream>>>(
        XW, s_q, s_k, row_off, cidx, bias1, nullptr, x1, nullptr, 0.01f, Nn);

    // skip path: skipb = lrelu(x_in@skip_w1+b1)@skip_w2+b2  (bf16)
    gemm_direct_kernel<<<dim3(gemm1_blocks), 256, 0, stream>>>(
        x_in, sw1t, 0L, sh, 0L, skip_b1, 0.01f, Nn, 2, mb);
    gemm_direct_kernel<<<dim3(gemm1_blocks), 256, 0, stream>>>(
        sh, sw2t, 0L, skipb, 0L, skip_b2, 1.0f, Nn, 2, mb);

    // layer 2: XW = x1 @ w2[r]
    gemm_direct_kernel<<<dim3(gemmR_blocks), 256, 0, stream>>>(
        x1, w2t, 65536L, XW, (long)Nn * 256, nullptr, 1.0f, Nn, R2, mb);
    sqk_kernel<<<dim3((Nn + 31) / 32, R), 256, 0, stream>>>(XW, q2, k2, s_q, s_k, Nn);
    agg_kernel<<<dim3((Nn + 3) / 4), 256, 0, stream>>>(
        XW, s_q, s_k, row_off, cidx, bias2, skipb, nullptr, (float*)d_out, 0.01f, Nn);
}

// Round 5
// 493.359 us; speedup vs baseline: 1.2219x; 1.2219x over previous
//
#include <hip/hip_runtime.h>
#include <hip/hip_bf16.h>

typedef __bf16 bf16x8 __attribute__((ext_vector_type(8)));
typedef float  f32x4  __attribute__((ext_vector_type(4)));

__device__ __forceinline__ void async_cp16(const __bf16* g, __bf16* l) {
    // C-style casts -> addrspacecast (reinterpret_cast across AS is rejected by clang)
    __builtin_amdgcn_global_load_lds(
        (const __attribute__((address_space(1))) void*)g,
        (__attribute__((address_space(3))) void*)l, 16, 0, 0);
}

// ---------------- build x_in(bf16) = [kg_emb[node_id] | ccle_mlp(ccle)[node_id]] ----------------
__global__ __launch_bounds__(256) void build_x_kernel(
    const float* __restrict__ kg_emb, const float* __restrict__ ccle,
    const float* __restrict__ cw1, const float* __restrict__ cb1,
    const float* __restrict__ cw2, const float* __restrict__ cb2,
    const int* __restrict__ node_id, __bf16* __restrict__ x_in, int Nn)
{
    __shared__ float h[2][32];
    int sub = threadIdx.x >> 7;       // 2 nodes per block
    int t   = threadIdx.x & 127;
    int i   = blockIdx.x * 2 + sub;
    if (i < Nn && t < 32) {
        int kid = node_id[i];
        float a = 0.f;
        #pragma unroll
        for (int j = 0; j < 4; j++) a += ccle[kid*4 + j] * cw1[j*32 + t];
        a += cb1[t];
        h[sub][t] = a < 0.f ? 0.01f * a : a;
    }
    __syncthreads();
    if (i < Nn) {
        int kid = node_id[i];
        x_in[i*256 + t] = (__bf16)kg_emb[kid*128 + t];
        float a = 0.f;
        #pragma unroll
        for (int j = 0; j < 32; j++) a += h[sub][j] * cw2[j*128 + t];
        a += cb2[t];
        x_in[i*256 + 128 + t] = (__bf16)a;
    }
}

// ---------------- CSR build ----------------
__global__ void hist_kernel(const int* __restrict__ ei, int* __restrict__ deg, int E) {
    int e = blockIdx.x * 256 + threadIdx.x;
    if (e < E) atomicAdd(&deg[ei[E + e]], 1);
}

__global__ __launch_bounds__(1024) void scan_kernel(
    const int* __restrict__ deg, int* __restrict__ row_off, int* __restrict__ cursor, int Nn)
{
    __shared__ int wsum[16];
    __shared__ int carry_s;
    int t = threadIdx.x;
    int lane = t & 63, wid = t >> 6;
    if (t == 0) carry_s = 0;
    __syncthreads();
    for (int base = 0; base < Nn; base += 1024) {
        int idx = base + t;
        int v = (idx < Nn) ? deg[idx] : 0;
        int incl = v;
        #pragma unroll
        for (int off = 1; off < 64; off <<= 1) {
            int x = __shfl_up(incl, off, 64);
            if (lane >= off) incl += x;
        }
        if (lane == 63) wsum[wid] = incl;
        __syncthreads();
        if (wid == 0) {
            int wv = (lane < 16) ? wsum[lane] : 0;
            #pragma unroll
            for (int off = 1; off < 16; off <<= 1) {
                int x = __shfl_up(wv, off, 64);
                if (lane >= off) wv += x;
            }
            if (lane < 16) wsum[lane] = wv;
        }
        __syncthreads();
        int wprefix = (wid > 0) ? wsum[wid - 1] : 0;
        int excl = carry_s + wprefix + incl - v;
        if (idx < Nn) { row_off[idx] = excl; cursor[idx] = excl; }
        __syncthreads();
        if (t == 1023) carry_s += wsum[15];
        __syncthreads();
    }
    if (t == 0) row_off[Nn] = carry_s;
}

__global__ void scatter_kernel(const int* __restrict__ ei, const int* __restrict__ et,
                               int* __restrict__ cursor, int* __restrict__ cidx, int E) {
    int e = blockIdx.x * 256 + threadIdx.x;
    if (e < E) {
        int d = ei[E + e];
        int pos = atomicAdd(&cursor[d], 1);
        cidx[pos] = (et[e] << 20) | ei[e];   // src < 2^20, et < 8
    }
}

// ---------------- 64x64-tile transpose + fp32->bf16 convert ----------------
__global__ __launch_bounds__(256) void transpose_kernel(
    const float* __restrict__ B, __bf16* __restrict__ Bt)
{
    __shared__ __bf16 tile[64][65];
    int z = blockIdx.z;
    int kb = blockIdx.x * 64;
    int nb = blockIdx.y * 64;
    int t = threadIdx.x;
    const float* Bz = B + z * 65536;
    __bf16* Btz = Bt + z * 65536;
    for (int idx = t; idx < 4096; idx += 256) {
        int rr = idx >> 6, cc = idx & 63;
        tile[rr][cc] = (__bf16)Bz[(kb + rr) * 256 + nb + cc];
    }
    __syncthreads();
    for (int idx = t; idx < 4096; idx += 256) {
        int rr = idx >> 6, cc = idx & 63;
        Btz[(nb + rr) * 256 + kb + cc] = tile[cc][rr];
    }
}

// ---------------- MFMA GEMM: LDS-staged via global_load_lds, double-buffered ----------------
// C[z][M][256] = A[M][256] @ Bt[z][256][256]^T, tile 128x128, BK=32.
// XCD swizzle: id%8 = XCD; the R2 blocks sharing one A-tile get consecutive slots
// on one XCD so A re-reads hit that XCD's L2 (R3-proven: FETCH 85->15 MB).
// LDS layout per buffer: A[128][32] then B[128][32], unpadded -> each MFMA frag
// read is a contiguous 1KB ds_read_b128 group (conflict-free); matches the
// wave-uniform-base + lane*16 constraint of global_load_lds.
__global__ __launch_bounds__(256, 3) void gemm_lds_kernel(
    const __bf16* __restrict__ A,
    const __bf16* __restrict__ Bt, long bStride,
    __bf16* __restrict__ C, long cStride,
    const float* __restrict__ bias, float slope,
    int M, int R2, int mb)
{
    __shared__ __bf16 sm[2][8192];   // [buf][A 4096 | B 4096] elements, 16 KB each
    const int id = blockIdx.x;
    const int xcd = id & 7, slot = id >> 3;
    const int g = xcd + 8 * (slot / R2);
    const int member = slot % R2;
    if (g >= mb) return;
    const int m0 = g * 128, n0 = (member & 1) * 128;
    const int z = member >> 1;
    const __bf16* __restrict__ Bb = Bt + (long)z * bStride;

    const int t = threadIdx.x;
    const int wave = t >> 6, lane = t & 63;
    const int wy = (wave >> 1) * 64, wx = (wave & 1) * 64;
    const int lr = lane & 15, lq = lane >> 4;

    // staging: chunk c in [0,512): row=c>>2, kc=(c&3)*8; lds elem off = c*8.
    // wave w covers chunks [w*128, w*128+128) via 2 instrs (A) + 2 (B).
    int c0 = wave * 128 + lane;            // +0 and +64
    int ar0 = m0 + (c0 >> 2);        if (ar0 >= M) ar0 = M - 1;
    int ar1 = m0 + ((c0 + 64) >> 2); if (ar1 >= M) ar1 = M - 1;
    int akc0 = (c0 & 3) << 3, akc1 = ((c0 + 64) & 3) << 3;
    int br0 = n0 + (c0 >> 2), br1 = n0 + ((c0 + 64) >> 2);
    const long a_g0 = (long)ar0 * 256 + akc0, a_g1 = (long)ar1 * 256 + akc1;
    const long b_g0 = (long)br0 * 256 + akc0, b_g1 = (long)br1 * 256 + akc1;
    const int lds_w0 = (wave * 128) * 8, lds_w1 = (wave * 128 + 64) * 8;

    f32x4 acc[4][4];
    #pragma unroll
    for (int a_ = 0; a_ < 4; a_++)
        #pragma unroll
        for (int b_ = 0; b_ < 4; b_++) acc[a_][b_] = (f32x4){0.f, 0.f, 0.f, 0.f};

    // prologue: stage k0=0 into buf 0
    async_cp16(A  + a_g0, &sm[0][lds_w0]);
    async_cp16(A  + a_g1, &sm[0][lds_w1]);
    async_cp16(Bb + b_g0, &sm[0][4096 + lds_w0]);
    async_cp16(Bb + b_g1, &sm[0][4096 + lds_w1]);

    #pragma unroll
    for (int it = 0; it < 8; it++) {
        const int cur = it & 1;
        __syncthreads();               // drains the stage for 'cur'
        if (it < 7) {                  // prefetch next chunk into the other buffer
            const int k0 = (it + 1) * 32;
            async_cp16(A  + a_g0 + k0, &sm[cur ^ 1][lds_w0]);
            async_cp16(A  + a_g1 + k0, &sm[cur ^ 1][lds_w1]);
            async_cp16(Bb + b_g0 + k0, &sm[cur ^ 1][4096 + lds_w0]);
            async_cp16(Bb + b_g1 + k0, &sm[cur ^ 1][4096 + lds_w1]);
        }
        bf16x8 af[4], bfr[4];
        #pragma unroll
        for (int tm = 0; tm < 4; tm++)
            af[tm] = *(const bf16x8*)(&sm[cur][(wy + tm * 16 + lr) * 32 + lq * 8]);
        #pragma unroll
        for (int tn = 0; tn < 4; tn++)
            bfr[tn] = *(const bf16x8*)(&sm[cur][4096 + (wx + tn * 16 + lr) * 32 + lq * 8]);
        #pragma unroll
        for (int tm = 0; tm < 4; tm++)
            #pragma unroll
            for (int tn = 0; tn < 4; tn++)
                acc[tm][tn] = __builtin_amdgcn_mfma_f32_16x16x32_bf16(af[tm], bfr[tn], acc[tm][tn], 0, 0, 0);
        __syncthreads();               // all waves done reading 'cur' before it is restaged
    }

    __bf16* __restrict__ Cb = C + (long)z * cStride;
    #pragma unroll
    for (int tm = 0; tm < 4; tm++) {
        #pragma unroll
        for (int tn = 0; tn < 4; tn++) {
            int col = n0 + wx + tn * 16 + lr;
            float bcol = bias ? bias[col] : 0.f;
            #pragma unroll
            for (int ii = 0; ii < 4; ii++) {
                int rg = m0 + wy + tm * 16 + lq * 4 + ii;
                if (rg < M) {
                    float v = acc[tm][tn][ii] + bcol;
                    v = v < 0.f ? v * slope : v;
                    Cb[(long)rg * 256 + col] = (__bf16)v;
                }
            }
        }
    }
}

// ---------------- s_q[r,n,h] = xw[r,n,:]@q[:,h], s_k likewise ----------------
__global__ __launch_bounds__(256) void sqk_kernel(
    const __bf16* __restrict__ XW, const float* __restrict__ q,
    const float* __restrict__ k, float* __restrict__ s_q,
    float* __restrict__ s_k, int Nn)
{
    __shared__ float qk[8][260];
    int t = threadIdx.x;
    for (int idx = t; idx < 2048; idx += 256) {
        int h8 = idx & 7, kk = idx >> 3;
        qk[h8][kk] = (h8 < 4) ? q[kk * 4 + h8] : k[kk * 4 + (h8 - 4)];
    }
    __syncthreads();
    int r = blockIdx.y;
    int node = blockIdx.x * 32 + (t >> 3);
    int h8 = t & 7;
    if (node >= Nn) return;
    const __bf16* row = XW + ((long)r * Nn + node) * 256;
    float acc = 0.f;
    for (int kb = 0; kb < 256; kb += 8) {
        uint4 pv = *(const uint4*)(row + kb);
        const __bf16* pp = (const __bf16*)&pv;
        #pragma unroll
        for (int j = 0; j < 8; j++) acc += (float)pp[j] * qk[h8][kb + j];
    }
    if (h8 < 4) s_q[((long)r * Nn + node) * 4 + h8] = acc;
    else        s_k[((long)r * Nn + node) * 4 + (h8 - 4)] = acc;
}

// ---------------- attention softmax + aggregation, one wave per node ----------------
__global__ __launch_bounds__(256) void agg_kernel(
    const __bf16* __restrict__ XW, const float* __restrict__ s_q,
    const float* __restrict__ s_k, const int* __restrict__ row_off,
    const int* __restrict__ cidx, const float* __restrict__ bias,
    const __bf16* __restrict__ skipb, __bf16* __restrict__ outb,
    float* __restrict__ outf, float slope, int Nn)
{
    int lane = threadIdx.x & 63;
    int i = blockIdx.x * 4 + (threadIdx.x >> 6);
    if (i >= Nn) return;
    int base = row_off[i];
    int deg = row_off[i + 1] - base;

    int half = lane >> 5;
    int l32 = lane & 31;
    int myh = l32 >> 3;          // head owning my 8 dims
    int d8 = l32 * 8;            // my dim offset within the 256-row

    float acc[8];
    #pragma unroll
    for (int u = 0; u < 8; u++) acc[u] = 0.f;
    float ss0 = 0.f, ss1 = 0.f, ss2 = 0.f, ss3 = 0.f;

    for (int c0 = 0; c0 < deg; c0 += 64) {
        int e = c0 + lane;
        float p0 = 0.f, p1 = 0.f, p2 = 0.f, p3 = 0.f;
        int cc = 0;
        if (e < deg) {
            cc = cidx[base + e];
            int src = cc & 0xFFFFF, et = cc >> 20;
            const float* sq = s_q + ((long)et * Nn + i) * 4;
            const float* sk = s_k + ((long)et * Nn + src) * 4;
            float l0 = sq[0] + sk[0]; l0 = l0 < 0.f ? 0.2f * l0 : l0;
            float l1 = sq[1] + sk[1]; l1 = l1 < 0.f ? 0.2f * l1 : l1;
            float l2 = sq[2] + sk[2]; l2 = l2 < 0.f ? 0.2f * l2 : l2;
            float l3 = sq[3] + sk[3]; l3 = l3 < 0.f ? 0.2f * l3 : l3;
            p0 = __expf(fminf(l0, 40.f)); p1 = __expf(fminf(l1, 40.f));
            p2 = __expf(fminf(l2, 40.f)); p3 = __expf(fminf(l3, 40.f));
        }
        ss0 += p0; ss1 += p1; ss2 += p2; ss3 += p3;
        int cnt = min(64, deg - c0);
        for (int j = 0; j < cnt; j += 2) {
            int srcl = j + half;             // lane holding my edge's p/cc (p=0 past tail)
            float q0 = __shfl(p0, srcl, 64);
            float q1 = __shfl(p1, srcl, 64);
            float q2 = __shfl(p2, srcl, 64);
            float q3 = __shfl(p3, srcl, 64);
            int   cj = __shfl(cc, srcl, 64);
            float w = (myh & 2) ? ((myh & 1) ? q3 : q2) : ((myh & 1) ? q1 : q0);
            int src = cj & 0xFFFFF, et = cj >> 20;
            bf16x8 xv = *(const bf16x8*)(XW + ((long)et * Nn + src) * 256 + d8);
            #pragma unroll
            for (int u = 0; u < 8; u++) acc[u] += w * (float)xv[u];
        }
    }
    // combine the two halves (each covered alternating edges of the same node)
    #pragma unroll
    for (int u = 0; u < 8; u++) acc[u] += __shfl_xor(acc[u], 32, 64);
    // reduce softmax denominators across the wave
    #pragma unroll
    for (int off = 32; off >= 1; off >>= 1) {
        ss0 += __shfl_xor(ss0, off, 64);
        ss1 += __shfl_xor(ss1, off, 64);
        ss2 += __shfl_xor(ss2, off, 64);
        ss3 += __shfl_xor(ss3, off, 64);
    }
    float ssh = (myh & 2) ? ((myh & 1) ? ss3 : ss2) : ((myh & 1) ? ss1 : ss0);
    float inv = 1.f / fmaxf(ssh, 1e-16f);

    float vout[8];
    #pragma unroll
    for (int u = 0; u < 8; u++) {
        float v = acc[u] * inv + bias[d8 + u];
        if (skipb) v += (float)skipb[(long)i * 256 + d8 + u];
        vout[u] = v < 0.f ? slope * v : v;
    }
    if (outb) {
        if (half == 0) {
            __bf16 tmp[8];
            #pragma unroll
            for (int u = 0; u < 8; u++) tmp[u] = (__bf16)vout[u];
            *(uint4*)(outb + (long)i * 256 + d8) = *(const uint4*)tmp;
        }
    } else {
        float4 f4;
        if (half == 0) { f4 = make_float4(vout[0], vout[1], vout[2], vout[3]);
                         *(float4*)(outf + (long)i * 256 + d8) = f4; }
        else           { f4 = make_float4(vout[4], vout[5], vout[6], vout[7]);
                         *(float4*)(outf + (long)i * 256 + d8 + 4) = f4; }
    }
}

extern "C" void kernel_launch(void* const* d_in, const int* in_sizes, int n_in,
                              void* d_out, int out_size, void* d_ws, size_t ws_size,
                              hipStream_t stream)
{
    const float* kg_emb  = (const float*)d_in[0];
    const float* ccle    = (const float*)d_in[1];
    const int*   node_id = (const int*)d_in[2];
    const int*   edge_ix = (const int*)d_in[3];
    const int*   edge_ty = (const int*)d_in[4];
    const float* ccle_w1 = (const float*)d_in[5];
    const float* ccle_b1 = (const float*)d_in[6];
    const float* ccle_w2 = (const float*)d_in[7];
    const float* ccle_b2 = (const float*)d_in[8];
    const float* w1      = (const float*)d_in[9];
    const float* q1      = (const float*)d_in[10];
    const float* k1      = (const float*)d_in[11];
    const float* bias1   = (const float*)d_in[12];
    const float* w2      = (const float*)d_in[13];
    const float* q2      = (const float*)d_in[14];
    const float* k2      = (const float*)d_in[15];
    const float* bias2   = (const float*)d_in[16];
    const float* skip_w1 = (const float*)d_in[17];
    const float* skip_b1 = (const float*)d_in[18];
    const float* skip_w2 = (const float*)d_in[19];
    const float* skip_b2 = (const float*)d_in[20];

    const int Nn = in_sizes[2];
    const int E  = in_sizes[4];
    const int R  = in_sizes[9] / (256 * 256);

    // workspace carve
    char* p = (char*)d_ws;
    auto alloc = [&](size_t bytes) { char* r = p; p += (bytes + 255) & ~(size_t)255; return r; };
    __bf16* x_in  = (__bf16*)alloc((size_t)Nn * 256 * 2);
    __bf16* x1    = (__bf16*)alloc((size_t)Nn * 256 * 2);
    __bf16* sh    = (__bf16*)alloc((size_t)Nn * 256 * 2);
    __bf16* skipb = (__bf16*)alloc((size_t)Nn * 256 * 2);
    __bf16* XW    = (__bf16*)alloc((size_t)R * Nn * 256 * 2);
    float*  s_q   = (float*)alloc((size_t)R * Nn * 4 * 4);
    float*  s_k   = (float*)alloc((size_t)R * Nn * 4 * 4);
    __bf16* w1t   = (__bf16*)alloc((size_t)R * 65536 * 2);
    __bf16* w2t   = (__bf16*)alloc((size_t)R * 65536 * 2);
    __bf16* sw1t  = (__bf16*)alloc((size_t)65536 * 2);
    __bf16* sw2t  = (__bf16*)alloc((size_t)65536 * 2);
    int* deg     = (int*)alloc((size_t)Nn * 4);
    int* row_off = (int*)alloc((size_t)(Nn + 1) * 4);
    int* cursor  = (int*)alloc((size_t)Nn * 4);
    int* cidx    = (int*)alloc((size_t)E * 4);

    const int mb = (Nn + 127) / 128;
    const int eb = (E + 255) / 256;
    const int grp = (mb + 7) / 8;
    const int R2 = 2 * R;
    const int gemmR_blocks = 8 * grp * R2;   // batched-R gemm
    const int gemm1_blocks = 8 * grp * 2;    // single-matrix gemm

    (void)hipMemsetAsync(deg, 0, (size_t)Nn * 4, stream);
    build_x_kernel<<<dim3((Nn + 1) / 2), 256, 0, stream>>>(
        kg_emb, ccle, ccle_w1, ccle_b1, ccle_w2, ccle_b2, node_id, x_in, Nn);
    hist_kernel<<<dim3(eb), 256, 0, stream>>>(edge_ix, deg, E);
    scan_kernel<<<dim3(1), 1024, 0, stream>>>(deg, row_off, cursor, Nn);
    scatter_kernel<<<dim3(eb), 256, 0, stream>>>(edge_ix, edge_ty, cursor, cidx, E);
    transpose_kernel<<<dim3(4, 4, R), 256, 0, stream>>>(w1, w1t);
    transpose_kernel<<<dim3(4, 4, R), 256, 0, stream>>>(w2, w2t);
    transpose_kernel<<<dim3(4, 4, 1), 256, 0, stream>>>(skip_w1, sw1t);
    transpose_kernel<<<dim3(4, 4, 1), 256, 0, stream>>>(skip_w2, sw2t);

    // layer 1: XW = x_in @ w1[r]
    gemm_lds_kernel<<<dim3(gemmR_blocks), 256, 0, stream>>>(
        x_in, w1t, 65536L, XW, (long)Nn * 256, nullptr, 1.0f, Nn, R2, mb);
    sqk_kernel<<<dim3((Nn + 31) / 32, R), 256, 0, stream>>>(XW, q1, k1, s_q, s_k, Nn);
    agg_kernel<<<dim3((Nn + 3) / 4), 256, 0, stream>>>(
        XW, s_q, s_k, row_off, cidx, bias1, nullptr, x1, nullptr, 0.01f, Nn);

    // skip path: skipb = lrelu(x_in@skip_w1+b1)@skip_w2+b2  (bf16)
    gemm_lds_kernel<<<dim3(gemm1_blocks), 256, 0, stream>>>(
        x_in, sw1t, 0L, sh, 0L, skip_b1, 0.01f, Nn, 2, mb);
    gemm_lds_kernel<<<dim3(gemm1_blocks), 256, 0, stream>>>(
        sh, sw2t, 0L, skipb, 0L, skip_b2, 1.0f, Nn, 2, mb);

    // layer 2: XW = x1 @ w2[r]
    gemm_lds_kernel<<<dim3(gemmR_blocks), 256, 0, stream>>>(
        x1, w2t, 65536L, XW, (long)Nn * 256, nullptr, 1.0f, Nn, R2, mb);
    sqk_kernel<<<dim3((Nn + 31) / 32, R), 256, 0, stream>>>(XW, q2, k2, s_q, s_k, Nn);
    agg_kernel<<<dim3((Nn + 3) / 4), 256, 0, stream>>>(
        XW, s_q, s_k, row_off, cidx, bias2, skipb, nullptr, (float*)d_out, 0.01f, Nn);
}